// Round 10
// baseline (2100.013 us; speedup 1.0000x reference)
//
#include <hip/hip_runtime.h>

#define EPSV 1e-5f
#define SCOPE_AGENT __HIP_MEMORY_SCOPE_AGENT

__device__ __forceinline__ float fast_rcp(float x) { return __builtin_amdgcn_rcpf(x); }
__device__ __forceinline__ float tanhfast(float x) {
    float e = __expf(2.0f * x);
    return 1.0f - 2.0f * fast_rcp(e + 1.0f);
}
__device__ __forceinline__ float dot4(const float4 w, const float4 v, float a) {
    a = fmaf(w.x, v.x, a);
    a = fmaf(w.y, v.y, a);
    a = fmaf(w.z, v.z, a);
    a = fmaf(w.w, v.w, a);
    return a;
}
#define DPPF(v, ctrl) __int_as_float(__builtin_amdgcn_mov_dpp(__float_as_int(v), (ctrl), 0xF, 0xF, false))

typedef unsigned long long ull;

__device__ __forceinline__ float aldf(const float* p) {
    return __hip_atomic_load(p, __ATOMIC_RELAXED, SCOPE_AGENT);
}
__device__ __forceinline__ void astf(float* p, float v) {
    __hip_atomic_store(p, v, __ATOMIC_RELAXED, SCOPE_AGENT);
}
__device__ __forceinline__ ull aldu(const ull* p) {
    return __hip_atomic_load(p, __ATOMIC_RELAXED, SCOPE_AGENT);
}
__device__ __forceinline__ void astu(ull* p, ull v) {
    __hip_atomic_store(p, v, __ATOMIC_RELAXED, SCOPE_AGENT);
}

// ---- LDS overlays ----
struct RecS {
    float hbuf[2][80];
    float ring[16][64];
    float xst[16][80];
};
struct GemS {
    float Uc[32 * 72];   // [k][72-pad t]
    float xt[128];
    float sc1[64], tc1[64];
    float psum[64 * 16];
};

// ------- pack: w2t2, w3p4/w3p1, zero sync ints (5120) -------
__global__ void pack_kernel(const float* __restrict__ w2, const float* __restrict__ w3,
                            float* __restrict__ w2t2, float4* __restrict__ w3p4,
                            float* __restrict__ w3p1, int* __restrict__ sync_ints) {
    int j = blockIdx.x * 256 + threadIdx.x;
    if (j < 16384) {
        int i = j >> 8;
        int o = (j >> 3) & 31;
        int k = j & 7;
        w2t2[j] = (k < 7) ? w2[o * 448 + i * 7 + k] : 0.0f;
    } else if (j < 16896) {
        int e = j - 16384;
        int i = e >> 4, o = e & 15;
        int base = o * 160 + i * 5;
        w3p4[e] = make_float4(w3[base], w3[base + 1], w3[base + 2], w3[base + 3]);
        w3p1[e] = w3[base + 4];
    } else if (j < 16896 + 5120) {
        sync_ints[j - 16896] = 0;
    }
}

// ------- pack edge-GEMM dense weights (k-major, 256-padded out rows) -------
// W2L (640x256): rows p*32+o (p<7). cols<256: q'=c>>6 (0..3, a1L), i=c&63, j=q'-p+3.
//   cols>=256: d=(c-256)>>6 (a1f t+d, q'=d+4), j=d+7-p valid iff d<=p-1.
// W2R (640x256): rows pp*32+o (p=43+pp). cols<384: d=c>>6 (a1f t+36+d, q'=40+d), j=d-pp iff d>=pp.
//   cols>=384: qq (a1R q'=46+qq), j=6+qq-pp iff qq<=pp.
// W3L (448x256): rows p3*16+o (p3<9). cols<224: p'=c>>5 (a2L), m=p'-p3+2 in [0,4].
//   cols>=224: d=(c-224)>>5 (a2f t+d, p'=7+d), m=9+d-p3 iff d<=p3-5 (and >=0).
// W3R (352x256): rows pp3*16+o (p3=41+pp3). cols<128: d=c>>5 (a2f t+32+d, p'=39+d), m=d-pp3 iff d>=pp3.
//   cols>=128: q (a2R p'=43+q), m=4+q-pp3 in [0,4].
__global__ void pack_edgeW_kernel(const float* __restrict__ w2, const float* __restrict__ w3,
                                  float* __restrict__ W2L, float* __restrict__ W2R,
                                  float* __restrict__ W3L, float* __restrict__ W3R) {
    int g = blockIdx.x * 256 + threadIdx.x;
    if (g < 163840) {
        int k = g >> 8, row = g & 255;
        float v = 0.0f;
        if (row < 224) {
            int p = row >> 5, o = row & 31;
            if (k < 256) {
                int q = k >> 6, i = k & 63, j = q - p + 3;
                if (j >= 0 && j <= 6) v = w2[o * 448 + i * 7 + j];
            } else {
                int d = (k - 256) >> 6, i = k & 63;
                if (d <= p - 1) v = w2[o * 448 + i * 7 + (d + 7 - p)];
            }
        }
        W2L[g] = v;
    } else if (g < 327680) {
        int e = g - 163840;
        int k = e >> 8, row = e & 255;
        float v = 0.0f;
        if (row < 224) {
            int pp = row >> 5, o = row & 31;
            if (k < 384) {
                int d = k >> 6, i = k & 63;
                if (d >= pp && d - pp <= 6) v = w2[o * 448 + i * 7 + (d - pp)];
            } else {
                int qq = (k - 384) >> 6, i = k & 63;
                if (qq <= pp) v = w2[o * 448 + i * 7 + (6 + qq - pp)];
            }
        }
        W2R[e] = v;
    } else if (g < 327680 + 114688) {
        int e = g - 327680;
        int k = e >> 8, row = e & 255;
        float v = 0.0f;
        if (row < 144) {
            int p3 = row >> 4, o = row & 15;
            if (k < 224) {
                int pp_ = k >> 5, i = k & 31, m = pp_ - p3 + 2;
                if (m >= 0 && m <= 4) v = w3[o * 160 + i * 5 + m];
            } else {
                int d = (k - 224) >> 5, i = k & 31, m = 9 + d - p3;
                if (m >= 0 && m <= 4) v = w3[o * 160 + i * 5 + m];
            }
        }
        W3L[e] = v;
    } else if (g < 327680 + 114688 + 90112) {
        int e = g - 327680 - 114688;
        int k = e >> 8, row = e & 255;
        float v = 0.0f;
        if (row < 144) {
            int pp3 = row >> 4, o = row & 15;
            if (k < 128) {
                int d = k >> 5, i = k & 31, m = d - pp3;
                if (m >= 0 && m <= 4) v = w3[o * 160 + i * 5 + m];
            } else {
                int q = (k - 128) >> 5, i = k & 31, m = 4 + q - pp3;
                if (m >= 0 && m <= 4) v = w3[o * 160 + i * 5 + m];
            }
        }
        W3R[e] = v;
    }
}

// ---------------- full-seq conv1/2/3 (verbatim R9) ----------------
__global__ __launch_bounds__(256) void conv1f_kernel(
    const float* __restrict__ x, const float* __restrict__ w1,
    const float* __restrict__ b1, const float* __restrict__ g1,
    const float* __restrict__ be1, const float* __restrict__ m1,
    const float* __restrict__ vv1, float* __restrict__ a1f)
{
    __shared__ float xs[72];
    const int tid = threadIdx.x;
    const int T = blockIdx.x * 64;
    const int b = blockIdx.y;
    if (tid < 72) {
        int gi = T - 49 + tid;
        xs[tid] = (gi >= 0 && gi < 2048) ? x[b * 2048 + gi] : 0.0f;
    }
    const int i = tid & 63, q = tid >> 6;
    float wv[9];
    #pragma unroll
    for (int k = 0; k < 9; ++k) wv[k] = w1[i * 9 + k];
    float sc = g1[i] * rsqrtf(vv1[i] + EPSV);
    float tc = (b1[i] - m1[i]) * sc + be1[i];
    __syncthreads();
    #pragma unroll
    for (int r = 0; r < 16; ++r) {
        int v1 = T + q * 16 + r;
        if (v1 < 2089) {
            float acc = 0.0f;
            #pragma unroll
            for (int k = 0; k < 9; ++k) acc = fmaf(wv[k], xs[q * 16 + r + k], acc);
            a1f[((long)b * 2089 + v1) * 64 + i] = fmaxf(acc * sc + tc, 0.0f);
        }
    }
}

__global__ __launch_bounds__(256) void conv2f_kernel(
    const float* __restrict__ a1f, const float* __restrict__ w2t2,
    const float* __restrict__ b2, const float* __restrict__ g2,
    const float* __restrict__ be2, const float* __restrict__ m2,
    const float* __restrict__ vv2, float* __restrict__ a2f)
{
    __shared__ __align__(16) float As[64 * 104];
    const int tid = threadIdx.x;
    const int T = blockIdx.x * 64;
    const int b = blockIdx.y;
    for (int idx = tid; idx < 1120; idx += 256) {
        int j = idx >> 4, i4 = (idx & 15) * 4;
        int v1 = T + j; if (v1 > 2088) v1 = 2088;
        float4 f = *(const float4*)&a1f[((long)b * 2089 + v1) * 64 + i4];
        int sj = j + ((j >> 3) << 2);
        As[(i4 + 0) * 104 + sj] = f.x;
        As[(i4 + 1) * 104 + sj] = f.y;
        As[(i4 + 2) * 104 + sj] = f.z;
        As[(i4 + 3) * 104 + sj] = f.w;
    }
    const int o = tid >> 3, pg = tid & 7;
    float sc = g2[o] * rsqrtf(vv2[o] + EPSV);
    float tc = (b2[o] - m2[o]) * sc + be2[o];
    __syncthreads();
    float acc[8];
    #pragma unroll
    for (int q = 0; q < 8; ++q) acc[q] = 0.0f;
    for (int i = 0; i < 64; ++i) {
        const float* rowp = &As[i * 104 + 12 * pg];
        float4 A0 = *(const float4*)&rowp[0];
        float4 A1 = *(const float4*)&rowp[4];
        float4 A2 = *(const float4*)&rowp[12];
        float2 A3 = *(const float2*)&rowp[16];
        const float4* wp = (const float4*)&w2t2[(i * 32 + o) * 8];
        float4 Wa = wp[0], Wb = wp[1];
        float av[14] = {A0.x, A0.y, A0.z, A0.w, A1.x, A1.y, A1.z, A1.w,
                        A2.x, A2.y, A2.z, A2.w, A3.x, A3.y};
        float wk[7] = {Wa.x, Wa.y, Wa.z, Wa.w, Wb.x, Wb.y, Wb.z};
        #pragma unroll
        for (int k = 0; k < 7; ++k) {
            #pragma unroll
            for (int q = 0; q < 8; ++q) acc[q] = fmaf(wk[k], av[q + k], acc[q]);
        }
    }
    #pragma unroll
    for (int q = 0; q < 8; ++q) {
        int v2 = T + pg * 8 + q;
        if (v2 < 2083)
            a2f[((long)b * 2083 + v2) * 32 + o] = fmaxf(acc[q] * sc + tc, 0.0f);
    }
}

__global__ __launch_bounds__(256) void conv3f_kernel(
    const float* __restrict__ a2f,
    const float4* __restrict__ w3p4, const float* __restrict__ w3p1,
    const float* __restrict__ b3, const float* __restrict__ g3,
    const float* __restrict__ be3, const float* __restrict__ m3,
    const float* __restrict__ vv3, float* __restrict__ a3f)
{
    __shared__ __align__(16) float A2s[32 * 200];
    const int tid = threadIdx.x;
    const int T = blockIdx.x * 128;
    const int b = blockIdx.y;
    for (int idx = tid; idx < 1056; idx += 256) {
        int j = idx >> 3, i4 = (idx & 7) * 4;
        int v2 = T + j; if (v2 > 2082) v2 = 2082;
        float4 f = *(const float4*)&a2f[((long)b * 2083 + v2) * 32 + i4];
        int sj = j + ((j >> 3) << 2);
        A2s[(i4 + 0) * 200 + sj] = f.x;
        A2s[(i4 + 1) * 200 + sj] = f.y;
        A2s[(i4 + 2) * 200 + sj] = f.z;
        A2s[(i4 + 3) * 200 + sj] = f.w;
    }
    const int o = tid & 15, pg = tid >> 4;
    float sc = g3[o] * rsqrtf(vv3[o] + EPSV);
    float tc = (b3[o] - m3[o]) * sc + be3[o];
    __syncthreads();
    float acc[8];
    #pragma unroll
    for (int q = 0; q < 8; ++q) acc[q] = 0.0f;
    for (int i = 0; i < 32; ++i) {
        const float* rowp = &A2s[i * 200 + 12 * pg];
        float4 R0 = *(const float4*)&rowp[0];
        float4 R1 = *(const float4*)&rowp[4];
        float4 R2 = *(const float4*)&rowp[12];
        float av[12] = {R0.x, R0.y, R0.z, R0.w, R1.x, R1.y, R1.z, R1.w,
                        R2.x, R2.y, R2.z, R2.w};
        float4 wa = w3p4[i * 16 + o];
        float w4 = w3p1[i * 16 + o];
        #pragma unroll
        for (int q = 0; q < 8; ++q) {
            acc[q] = fmaf(wa.x, av[q], acc[q]);
            acc[q] = fmaf(wa.y, av[q + 1], acc[q]);
            acc[q] = fmaf(wa.z, av[q + 2], acc[q]);
            acc[q] = fmaf(wa.w, av[q + 3], acc[q]);
            acc[q] = fmaf(w4,   av[q + 4], acc[q]);
        }
    }
    #pragma unroll
    for (int q = 0; q < 8; ++q) {
        int v3 = T + pg * 8 + q;
        if (v3 < 2079)
            a3f[((long)b * 2080 + v3) * 16 + o] = fmaxf(acc[q] * sc + tc, 0.0f);
        else if (v3 < 2080)
            a3f[((long)b * 2080 + v3) * 16 + o] = 0.0f;
    }
}

// ================= rec bodies (verbatim R9) =================
__device__ __forceinline__ void rec0_body(char* smemraw, int b,
    const float* __restrict__ feats,
    const float* __restrict__ wih, const float* __restrict__ whh,
    const float* __restrict__ bih, const float* __restrict__ bhh,
    float* __restrict__ hout, int* __restrict__ cnt0, int* __restrict__ flag1)
{
    RecS* s = (RecS*)smemraw;
    const int tid = threadIdx.x;
    const int j = tid >> 2, kq = tid & 3;

    const float4* pa = (const float4*)(whh + (0 * 64 + j) * 64 + kq * 16);
    const float4* pb = (const float4*)(whh + (1 * 64 + j) * 64 + kq * 16);
    const float4* pc_ = (const float4*)(whh + (2 * 64 + j) * 64 + kq * 16);
    const float4* pd = (const float4*)(whh + (3 * 64 + j) * 64 + kq * 16);
    float4 A0 = pa[0], A1 = pa[1], A2 = pa[2], A3 = pa[3];
    float4 B0 = pb[0], B1 = pb[1], B2 = pb[2], B3 = pb[3];
    float4 C0 = pc_[0], C1 = pc_[1], C2 = pc_[2], C3 = pc_[3];
    float4 D0 = pd[0], D1 = pd[1], D2 = pd[2], D3 = pd[3];
    float4 xw0 = *(const float4*)(wih + (0 * 64 + j) * 16 + kq * 4);
    float4 xw1 = *(const float4*)(wih + (1 * 64 + j) * 16 + kq * 4);
    float4 xw2 = *(const float4*)(wih + (2 * 64 + j) * 16 + kq * 4);
    float4 xw3 = *(const float4*)(wih + (3 * 64 + j) * 16 + kq * 4);
    const float bb0 = bih[j] + bhh[j];
    const float bb1 = bih[64 + j] + bhh[64 + j];
    const float bb2 = bih[128 + j] + bhh[128 + j];
    const float bb3 = bih[192 + j] + bhh[192 + j];

    if (tid < 64) s->hbuf[1][(tid >> 4) * 20 + (tid & 15)] = 0.0f;
    float cst = 0.0f;
    const float* fbase = feats + (long)b * 32768;
    __syncthreads();

#define STEP0(k) { \
        const float4* hp_ = (const float4*)&s->hbuf[((k) + 1) & 1][kq * 20]; \
        float4 h0_ = hp_[0], h1_ = hp_[1], h2_ = hp_[2], h3_ = hp_[3]; \
        float4 xv_ = *(const float4*)&s->xst[(k)][kq * 4]; \
        float p0 = dot4(A3, h3_, dot4(A2, h2_, dot4(A1, h1_, dot4(A0, h0_, dot4(xw0, xv_, 0.f))))); \
        float p1 = dot4(B3, h3_, dot4(B2, h2_, dot4(B1, h1_, dot4(B0, h0_, dot4(xw1, xv_, 0.f))))); \
        float p2 = dot4(C3, h3_, dot4(C2, h2_, dot4(C1, h1_, dot4(C0, h0_, dot4(xw2, xv_, 0.f))))); \
        float p3 = dot4(D3, h3_, dot4(D2, h2_, dot4(D1, h1_, dot4(D0, h0_, dot4(xw3, xv_, 0.f))))); \
        p0 += DPPF(p0, 0xB1); p1 += DPPF(p1, 0xB1); p2 += DPPF(p2, 0xB1); p3 += DPPF(p3, 0xB1); \
        p0 += DPPF(p0, 0x4E); p1 += DPPF(p1, 0x4E); p2 += DPPF(p2, 0x4E); p3 += DPPF(p3, 0x4E); \
        float gi = 1.0f - fast_rcp(__expf(p0 + bb0) + 1.0f); \
        float gf = 1.0f - fast_rcp(__expf(p1 + bb1) + 1.0f); \
        float gg = 1.0f - 2.0f * fast_rcp(__expf(2.0f * (p2 + bb2)) + 1.0f); \
        float go = 1.0f - fast_rcp(__expf(p3 + bb3) + 1.0f); \
        cst = fmaf(gf, cst, gi * gg); \
        float h_ = go * tanhfast(cst); \
        if (kq == 0) { s->hbuf[(k) & 1][(j >> 4) * 20 + (j & 15)] = h_; s->ring[(k)][j] = h_; } \
        __syncthreads(); \
    }

    for (int c = 0; c < 128; ++c) {
        if (tid == 0) {
            while (__hip_atomic_load(&cnt0[b * 128 + c], __ATOMIC_RELAXED, SCOPE_AGENT) < 16)
                __builtin_amdgcn_s_sleep(2);
        }
        __syncthreads();
        s->xst[tid >> 4][tid & 15] = aldf(fbase + c * 256 + tid);
        __syncthreads();
        STEP0(0)  STEP0(1)  STEP0(2)  STEP0(3)
        STEP0(4)  STEP0(5)  STEP0(6)  STEP0(7)
        STEP0(8)  STEP0(9)  STEP0(10) STEP0(11)
        STEP0(12) STEP0(13) STEP0(14) STEP0(15)
        {
            ull* dst = (ull*)(hout + ((long)b * 2048 + c * 16) * 64);
            ull v0 = ((const ull*)s->ring)[tid];
            ull v1 = ((const ull*)s->ring)[tid + 256];
            astu(dst + tid, v0);
            astu(dst + tid + 256, v1);
            __syncthreads();
            if (tid == 0)
                __hip_atomic_store(&flag1[b * 128 + c], 1, __ATOMIC_RELAXED, SCOPE_AGENT);
        }
    }
#undef STEP0
}

__device__ __forceinline__ void rec1_body(char* smemraw, int b,
    const float* __restrict__ h1o,
    const float* __restrict__ wih, const float* __restrict__ whh,
    const float* __restrict__ bih, const float* __restrict__ bhh,
    float* __restrict__ hout, int* __restrict__ flag1)
{
    RecS* s = (RecS*)smemraw;
    const int tid = threadIdx.x;
    const int j = tid >> 2, kq = tid & 3;

    const float4* pa = (const float4*)(whh + (0 * 64 + j) * 64 + kq * 16);
    const float4* pb = (const float4*)(whh + (1 * 64 + j) * 64 + kq * 16);
    const float4* pc_ = (const float4*)(whh + (2 * 64 + j) * 64 + kq * 16);
    const float4* pd = (const float4*)(whh + (3 * 64 + j) * 64 + kq * 16);
    float4 A0 = pa[0], A1 = pa[1], A2 = pa[2], A3 = pa[3];
    float4 B0 = pb[0], B1 = pb[1], B2 = pb[2], B3 = pb[3];
    float4 C0 = pc_[0], C1 = pc_[1], C2 = pc_[2], C3 = pc_[3];
    float4 D0 = pd[0], D1 = pd[1], D2 = pd[2], D3 = pd[3];
    const float4* qa = (const float4*)(wih + (0 * 64 + j) * 64 + kq * 16);
    const float4* qb = (const float4*)(wih + (1 * 64 + j) * 64 + kq * 16);
    const float4* qc = (const float4*)(wih + (2 * 64 + j) * 64 + kq * 16);
    const float4* qd = (const float4*)(wih + (3 * 64 + j) * 64 + kq * 16);
    float4 XA0 = qa[0], XA1 = qa[1], XA2 = qa[2], XA3 = qa[3];
    float4 XB0 = qb[0], XB1 = qb[1], XB2 = qb[2], XB3 = qb[3];
    float4 XC0 = qc[0], XC1 = qc[1], XC2 = qc[2], XC3 = qc[3];
    float4 XD0 = qd[0], XD1 = qd[1], XD2 = qd[2], XD3 = qd[3];
    const float bb0 = bih[j] + bhh[j];
    const float bb1 = bih[64 + j] + bhh[64 + j];
    const float bb2 = bih[128 + j] + bhh[128 + j];
    const float bb3 = bih[192 + j] + bhh[192 + j];

    if (tid < 64) s->hbuf[1][(tid >> 4) * 20 + (tid & 15)] = 0.0f;
    float cst = 0.0f;
    __syncthreads();

#define STEP1(k) { \
        const float4* hp_ = (const float4*)&s->hbuf[((k) + 1) & 1][kq * 20]; \
        float4 h0_ = hp_[0], h1_ = hp_[1], h2_ = hp_[2], h3_ = hp_[3]; \
        const float4* xp_ = (const float4*)&s->xst[(k)][kq * 20]; \
        float4 x0_ = xp_[0], x1_ = xp_[1], x2_ = xp_[2], x3_ = xp_[3]; \
        float p0 = dot4(A3, h3_, dot4(A2, h2_, dot4(A1, h1_, dot4(A0, h0_, \
                   dot4(XA3, x3_, dot4(XA2, x2_, dot4(XA1, x1_, dot4(XA0, x0_, 0.f)))))))); \
        float p1 = dot4(B3, h3_, dot4(B2, h2_, dot4(B1, h1_, dot4(B0, h0_, \
                   dot4(XB3, x3_, dot4(XB2, x2_, dot4(XB1, x1_, dot4(XB0, x0_, 0.f)))))))); \
        float p2 = dot4(C3, h3_, dot4(C2, h2_, dot4(C1, h1_, dot4(C0, h0_, \
                   dot4(XC3, x3_, dot4(XC2, x2_, dot4(XC1, x1_, dot4(XC0, x0_, 0.f)))))))); \
        float p3 = dot4(D3, h3_, dot4(D2, h2_, dot4(D1, h1_, dot4(D0, h0_, \
                   dot4(XD3, x3_, dot4(XD2, x2_, dot4(XD1, x1_, dot4(XD0, x0_, 0.f)))))))); \
        p0 += DPPF(p0, 0xB1); p1 += DPPF(p1, 0xB1); p2 += DPPF(p2, 0xB1); p3 += DPPF(p3, 0xB1); \
        p0 += DPPF(p0, 0x4E); p1 += DPPF(p1, 0x4E); p2 += DPPF(p2, 0x4E); p3 += DPPF(p3, 0x4E); \
        float gi = 1.0f - fast_rcp(__expf(p0 + bb0) + 1.0f); \
        float gf = 1.0f - fast_rcp(__expf(p1 + bb1) + 1.0f); \
        float gg = 1.0f - 2.0f * fast_rcp(__expf(2.0f * (p2 + bb2)) + 1.0f); \
        float go = 1.0f - fast_rcp(__expf(p3 + bb3) + 1.0f); \
        cst = fmaf(gf, cst, gi * gg); \
        float h_ = go * tanhfast(cst); \
        if (kq == 0) { s->hbuf[(k) & 1][(j >> 4) * 20 + (j & 15)] = h_; s->ring[(k)][j] = h_; } \
        __syncthreads(); \
    }

    for (int c = 0; c < 128; ++c) {
        if (tid == 0) {
            while (__hip_atomic_load(&flag1[b * 128 + c], __ATOMIC_RELAXED, SCOPE_AGENT) < 1)
                __builtin_amdgcn_s_sleep(2);
        }
        __syncthreads();
        {
            const ull* src = (const ull*)(h1o + ((long)b * 2048 + c * 16) * 64);
            ull v0 = aldu(src + tid);
            ull v1 = aldu(src + tid + 256);
            int u0 = tid, u1 = tid + 256;
            int k0 = u0 >> 5, p0i = (u0 & 31) * 2;
            int k1 = u1 >> 5, p1i = (u1 & 31) * 2;
            *(ull*)&s->xst[k0][(p0i >> 4) * 20 + (p0i & 15)] = v0;
            *(ull*)&s->xst[k1][(p1i >> 4) * 20 + (p1i & 15)] = v1;
        }
        __syncthreads();
        STEP1(0)  STEP1(1)  STEP1(2)  STEP1(3)
        STEP1(4)  STEP1(5)  STEP1(6)  STEP1(7)
        STEP1(8)  STEP1(9)  STEP1(10) STEP1(11)
        STEP1(12) STEP1(13) STEP1(14) STEP1(15)
        {
            float4* dst = (float4*)(hout + ((long)b * 2048 + c * 16) * 64);
            dst[tid] = ((const float4*)s->ring)[tid];
        }
    }
#undef STEP1
}

// ================= edge GEMM body =================
// mode 0: a2L (K=640), 1: a2R (K=640), 2: a3L->edgeL (K=448), 3: a3R->edgeR (K=352).
// Block tile: 64 t x 256 out rows; thread (tg=tid>>5, og=tid&31) computes 8t x 8o.
__device__ void gemm_body(char* smemraw, int mode, int T, int b,
    const float* __restrict__ x, const float* __restrict__ w1g,
    const float* __restrict__ b1, const float* __restrict__ g1,
    const float* __restrict__ be1, const float* __restrict__ m1, const float* __restrict__ vv1,
    const float* __restrict__ b2, const float* __restrict__ g2,
    const float* __restrict__ be2, const float* __restrict__ m2, const float* __restrict__ vv2,
    const float* __restrict__ b3, const float* __restrict__ g3,
    const float* __restrict__ be3, const float* __restrict__ m3, const float* __restrict__ vv3,
    const float* __restrict__ W2L, const float* __restrict__ W2R,
    const float* __restrict__ W3L, const float* __restrict__ W3R,
    const float* __restrict__ a1f, const float* __restrict__ a2f,
    float* __restrict__ a2L, float* __restrict__ a2R,
    float* __restrict__ edgeL, float* __restrict__ edgeR,
    int* __restrict__ k2cnt, int* __restrict__ k3cnt)
{
    GemS* s = (GemS*)smemraw;
    const int tid = threadIdx.x;
    const int tg = tid >> 5, og = tid & 31;
    const int t0 = T * 64;

    if (mode <= 1) {
        if (tid < 128) {
            int gidx = t0 - 49 + tid;
            s->xt[tid] = (tid < 116 && gidx >= 0 && gidx < 2048) ? x[b * 2048 + gidx] : 0.0f;
        } else if (tid < 192) {
            int i = tid - 128;
            float sc = g1[i] * rsqrtf(vv1[i] + EPSV);
            s->sc1[i] = sc;
            s->tc1[i] = (b1[i] - m1[i]) * sc + be1[i];
        }
    } else {
        if (mode == 2) {   // wait for a2L+a2R of this (T,b)
            if (tid == 0) {
                while (__hip_atomic_load(&k2cnt[T * 16 + b], __ATOMIC_RELAXED, SCOPE_AGENT) < 2)
                    __builtin_amdgcn_s_sleep(2);
            }
        } else {
            if (tid == 0) {
                while (__hip_atomic_load(&k2cnt[T * 16 + b], __ATOMIC_RELAXED, SCOPE_AGENT) < 2)
                    __builtin_amdgcn_s_sleep(2);
            }
        }
        for (int e = tid; e < 1024; e += 256) s->psum[e] = 0.0f;
    }

    float acc[8][8];
    #pragma unroll
    for (int a_ = 0; a_ < 8; ++a_)
        #pragma unroll
        for (int o_ = 0; o_ < 8; ++o_) acc[a_][o_] = 0.0f;

    const int K = (mode <= 1) ? 640 : (mode == 2 ? 448 : 352);
    const float* Wg = (mode == 0) ? W2L : (mode == 1) ? W2R : (mode == 2) ? W3L : W3R;
    const int kst = tid >> 3, tb = (tid & 7) * 8;
    __syncthreads();

    for (int kc = 0; kc < K / 32; ++kc) {
        #pragma unroll
        for (int jj = 0; jj < 8; ++jj) {
            int tl = tb + jj;
            int col = kc * 32 + kst;
            int t = t0 + tl;
            float val;
            if (mode == 0) {
                if (col < 256) {
                    int q = col >> 6, i = col & 63;
                    float a = 0.0f;
                    for (int kk = 4 - q; kk <= 8; ++kk)
                        a = fmaf(w1g[i * 9 + kk], s->xt[tl + q + kk - 4], a);
                    val = fmaxf(a * s->sc1[i] + s->tc1[i], 0.0f);
                } else {
                    int d = (col - 256) >> 6, i = col & 63;
                    val = a1f[((long)b * 2089 + t + d) * 64 + i];
                }
            } else if (mode == 1) {
                if (col < 384) {
                    int d = col >> 6, i = col & 63;
                    val = a1f[((long)b * 2089 + t + 36 + d) * 64 + i];
                } else {
                    int q = (col - 384) >> 6, i = col & 63;
                    float a = 0.0f;
                    for (int kk = 0; kk <= 7 - q; ++kk)
                        a = fmaf(w1g[i * 9 + kk], s->xt[tl + 42 + q + kk], a);
                    val = fmaxf(a * s->sc1[i] + s->tc1[i], 0.0f);
                }
            } else if (mode == 2) {
                if (col < 224) val = aldf(a2L + ((long)b * 2048 + t) * 224 + col);
                else {
                    int d = (col - 224) >> 5;
                    val = a2f[((long)b * 2083 + t + d) * 32 + (col & 31)];
                }
            } else {
                if (col < 128) {
                    int d = col >> 5;
                    val = a2f[((long)b * 2083 + t + 32 + d) * 32 + (col & 31)];
                } else val = aldf(a2R + ((long)b * 2048 + t) * 224 + (col - 128));
            }
            s->Uc[kst * 72 + tl] = val;
        }
        __syncthreads();
        const float4* Wg4 = (const float4*)Wg;
        #pragma unroll 4
        for (int k = 0; k < 32; ++k) {
            int ka = kc * 32 + k;
            float4 w0 = Wg4[ka * 64 + og * 2];
            float4 w1v = Wg4[ka * 64 + og * 2 + 1];
            const float4* up = (const float4*)&s->Uc[k * 72 + tg * 8];
            float4 u0 = up[0], u1 = up[1];
            float ut[8] = {u0.x, u0.y, u0.z, u0.w, u1.x, u1.y, u1.z, u1.w};
            float wo[8] = {w0.x, w0.y, w0.z, w0.w, w1v.x, w1v.y, w1v.z, w1v.w};
            #pragma unroll
            for (int a_ = 0; a_ < 8; ++a_)
                #pragma unroll
                for (int o_ = 0; o_ < 8; ++o_)
                    acc[a_][o_] = fmaf(ut[a_], wo[o_], acc[a_][o_]);
        }
        __syncthreads();
    }

    if (mode <= 1) {
        if (og <= 27) {
            float s2v[8], t2v[8];
            #pragma unroll
            for (int oo = 0; oo < 8; ++oo) {
                int o = (og * 8 + oo) & 31;
                float sc = g2[o] * rsqrtf(vv2[o] + EPSV);
                s2v[oo] = sc;
                t2v[oo] = (b2[o] - m2[o]) * sc + be2[o];
            }
            float* dst = (mode == 0) ? a2L : a2R;
            #pragma unroll
            for (int tt = 0; tt < 8; ++tt) {
                long base = ((long)b * 2048 + t0 + tg * 8 + tt) * 224 + og * 8;
                #pragma unroll
                for (int oo = 0; oo < 8; oo += 2) {
                    float r0 = fmaxf(acc[tt][oo] * s2v[oo] + t2v[oo], 0.0f);
                    float r1 = fmaxf(acc[tt][oo + 1] * s2v[oo + 1] + t2v[oo + 1], 0.0f);
                    ull pv;
                    ((float*)&pv)[0] = r0;
                    ((float*)&pv)[1] = r1;
                    astu((ull*)(dst + base + oo), pv);
                }
            }
        }
        __syncthreads();
        if (tid == 0)
            __hip_atomic_fetch_add(&k2cnt[T * 16 + b], 1, __ATOMIC_RELAXED, SCOPE_AGENT);
    } else {
        int p3 = og >> 1;
        if (p3 <= 8) {
            int obase = (og & 1) * 8;
            float s3v[8], t3v[8];
            #pragma unroll
            for (int oo = 0; oo < 8; ++oo) {
                int o = obase + oo;
                float sc = g3[o] * rsqrtf(vv3[o] + EPSV);
                s3v[oo] = sc;
                t3v[oo] = (b3[o] - m3[o]) * sc + be3[o];
            }
            #pragma unroll
            for (int tt = 0; tt < 8; ++tt) {
                #pragma unroll
                for (int oo = 0; oo < 8; ++oo) {
                    float v = fmaxf(acc[tt][oo] * s3v[oo] + t3v[oo], 0.0f);
                    atomicAdd(&s->psum[(tg * 8 + tt) * 16 + obase + oo], v);
                }
            }
        }
        __syncthreads();
        {
            float* dst = (mode == 2) ? edgeL : edgeR;
            int tl = tid >> 2, o4 = (tid & 3) * 4;
            long base = ((long)b * 2048 + t0 + tl) * 16 + o4;
            const float* ps = &s->psum[tl * 16 + o4];
            ull p0, p1;
            ((float*)&p0)[0] = ps[0]; ((float*)&p0)[1] = ps[1];
            ((float*)&p1)[0] = ps[2]; ((float*)&p1)[1] = ps[3];
            astu((ull*)(dst + base), p0);
            astu((ull*)(dst + base + 2), p1);
        }
        __syncthreads();
        if (tid == 0)
            __hip_atomic_fetch_add(&k3cnt[T * 16 + b], 1, __ATOMIC_RELAXED, SCOPE_AGENT);
    }
}

// ================= K4: feats assembly =================
__device__ void k4_body(int b, int c,
    const float* __restrict__ a3f,
    const float* __restrict__ edgeL, const float* __restrict__ edgeR,
    float* __restrict__ feats, int* __restrict__ cnt0, int* __restrict__ k3cnt)
{
    const int tid = threadIdx.x;
    if (tid == 0) {
        while (__hip_atomic_load(&k3cnt[(c >> 2) * 16 + b], __ATOMIC_RELAXED, SCOPE_AGENT) < 2)
            __builtin_amdgcn_s_sleep(2);
    }
    __syncthreads();
    int tt = tid >> 4, o = tid & 15;
    int t = c * 16 + tt;
    float sum = 0.0f;
    #pragma unroll 8
    for (int d = 0; d < 32; ++d) sum += a3f[((long)b * 2080 + t + d) * 16 + o];
    sum += aldf(edgeL + ((long)b * 2048 + t) * 16 + o);
    sum += aldf(edgeR + ((long)b * 2048 + t) * 16 + o);
    astf(feats + ((long)b * 2048 + t) * 16 + o, sum * (1.0f / 50.0f));
    __syncthreads();   // drains vmcnt: feats visible before counter bump
    if (tid == 0)
        __hip_atomic_fetch_add(&cnt0[b * 128 + c], 16, __ATOMIC_RELAXED, SCOPE_AGENT);
}

// ================= fused =================
// blocks 0-15 rec0, 16-31 rec1; then 32 tile-groups x 128 blocks:
// r<16 K2L, <32 K2R, <48 K3L, <64 K3R, else K4 (b = (r-64)>>2, c = T*4+((r-64)&3)).
__global__ __launch_bounds__(256, 2) void fused_kernel(
    const float* __restrict__ x, const float* __restrict__ w1,
    const float* __restrict__ b1, const float* __restrict__ g1,
    const float* __restrict__ be1, const float* __restrict__ m1, const float* __restrict__ vv1,
    const float* __restrict__ b2, const float* __restrict__ g2,
    const float* __restrict__ be2, const float* __restrict__ m2, const float* __restrict__ vv2,
    const float* __restrict__ b3, const float* __restrict__ g3,
    const float* __restrict__ be3, const float* __restrict__ m3, const float* __restrict__ vv3,
    const float* __restrict__ W2L, const float* __restrict__ W2R,
    const float* __restrict__ W3L, const float* __restrict__ W3R,
    const float* __restrict__ a1f, const float* __restrict__ a2f, const float* __restrict__ a3f,
    float* __restrict__ a2L, float* __restrict__ a2R,
    float* __restrict__ edgeL, float* __restrict__ edgeR,
    const float* __restrict__ wih0, const float* __restrict__ whh0,
    const float* __restrict__ bih0, const float* __restrict__ bhh0,
    const float* __restrict__ wih1, const float* __restrict__ whh1,
    const float* __restrict__ bih1, const float* __restrict__ bhh1,
    float* __restrict__ feats, float* __restrict__ h1o, float* __restrict__ h2o,
    int* __restrict__ cnt0, int* __restrict__ flag1,
    int* __restrict__ k2cnt, int* __restrict__ k3cnt)
{
    __shared__ __align__(16) char smem[sizeof(GemS) > sizeof(RecS) ? sizeof(GemS) : sizeof(RecS)];

    const int bid = blockIdx.x;
    if (bid < 16) { rec0_body(smem, bid, feats, wih0, whh0, bih0, bhh0, h1o, cnt0, flag1); return; }
    if (bid < 32) { rec1_body(smem, bid - 16, h1o, wih1, whh1, bih1, bhh1, h2o, flag1); return; }
    int w = bid - 32;
    int T = w >> 7;
    int r = w & 127;
    if (r < 64) {
        int mode = r >> 4;           // 0:K2L 1:K2R 2:K3L 3:K3R
        int b = r & 15;
        gemm_body(smem, mode, T, b, x, w1, b1, g1, be1, m1, vv1,
                  b2, g2, be2, m2, vv2, b3, g3, be3, m3, vv3,
                  W2L, W2R, W3L, W3R, a1f, a2f, a2L, a2R, edgeL, edgeR, k2cnt, k3cnt);
    } else {
        int e = r - 64;
        k4_body(e >> 2, T * 4 + (e & 3), a3f, edgeL, edgeR, feats, cnt0, k3cnt);
    }
}

// ---------------- FC head ----------------
__global__ __launch_bounds__(256) void fc_kernel(
    const float* __restrict__ h2o,
    const float* __restrict__ fc1w, const float* __restrict__ fc1b,
    const float* __restrict__ fc2w, const float* __restrict__ fc2b,
    float* __restrict__ out)
{
    int r = blockIdx.x * 256 + threadIdx.x;
    float h[64];
    const float4* hp = (const float4*)(h2o + (long)r * 64);
    #pragma unroll
    for (int i = 0; i < 16; ++i) {
        float4 v = hp[i];
        h[4 * i] = v.x; h[4 * i + 1] = v.y; h[4 * i + 2] = v.z; h[4 * i + 3] = v.w;
    }
    float l0 = fc2b[0], l1 = fc2b[1];
    #pragma unroll 4
    for (int j = 0; j < 32; ++j) {
        float z = fc1b[j];
        #pragma unroll
        for (int k = 0; k < 64; ++k) z = fmaf(h[k], fc1w[j * 64 + k], z);
        z = fmaxf(z, 0.0f);
        l0 = fmaf(z, fc2w[j], l0);
        l1 = fmaf(z, fc2w[32 + j], l1);
    }
    out[r * 2] = l0;
    out[r * 2 + 1] = l1;
}

extern "C" void kernel_launch(void* const* d_in, const int* in_sizes, int n_in,
                              void* d_out, int out_size, void* d_ws, size_t ws_size,
                              hipStream_t stream) {
    const float* x    = (const float*)d_in[0];
    const float* w1   = (const float*)d_in[1];
    const float* b1   = (const float*)d_in[2];
    const float* g1   = (const float*)d_in[3];
    const float* be1  = (const float*)d_in[4];
    const float* m1   = (const float*)d_in[5];
    const float* v1   = (const float*)d_in[6];
    const float* w2   = (const float*)d_in[7];
    const float* b2   = (const float*)d_in[8];
    const float* g2   = (const float*)d_in[9];
    const float* be2  = (const float*)d_in[10];
    const float* m2   = (const float*)d_in[11];
    const float* v2   = (const float*)d_in[12];
    const float* w3   = (const float*)d_in[13];
    const float* b3   = (const float*)d_in[14];
    const float* g3   = (const float*)d_in[15];
    const float* be3  = (const float*)d_in[16];
    const float* m3   = (const float*)d_in[17];
    const float* v3   = (const float*)d_in[18];
    const float* wih0 = (const float*)d_in[19];
    const float* whh0 = (const float*)d_in[20];
    const float* bih0 = (const float*)d_in[21];
    const float* bhh0 = (const float*)d_in[22];
    const float* wih1 = (const float*)d_in[23];
    const float* whh1 = (const float*)d_in[24];
    const float* bih1 = (const float*)d_in[25];
    const float* bhh1 = (const float*)d_in[26];
    const float* fc1w = (const float*)d_in[27];
    const float* fc1b = (const float*)d_in[28];
    const float* fc2w = (const float*)d_in[29];
    const float* fc2b = (const float*)d_in[30];
    float* out = (float*)d_out;

    float* ws    = (float*)d_ws;
    float* feats = ws;                        // 524288
    float* h2o   = feats + 524288;            // 2097152
    float* h1o   = h2o + 2097152;             // 2097152
    float* w2t2  = h1o + 2097152;             // 16384
    float* w3p4f = w2t2 + 16384;              // 2048
    float* w3p1  = w3p4f + 2048;              // 512
    float* a1f   = w3p1 + 512;                // 16*2089*64 = 2139136
    float* a2f   = a1f + 2139136;             // 16*2083*32 = 1066496
    float* a3f   = a2f + 1066496;             // 16*2080*16 = 532480
    float* a2L   = a3f + 532480;              // 16*2048*224 = 7340032
    float* a2R   = a2L + 7340032;             // 7340032
    float* edgeL = a2R + 7340032;             // 524288
    float* edgeR = edgeL + 524288;            // 524288
    float* W2L   = edgeR + 524288;            // 163840
    float* W2R   = W2L + 163840;              // 163840
    float* W3L   = W2R + 163840;              // 114688
    float* W3R   = W3L + 114688;              // 90112
    int*   sync_ = (int*)(W3R + 90112);       // 5120 ints
    int*   cnt0  = sync_;                     // 2048
    int*   flag1 = sync_ + 2048;              // 2048
    int*   k2cnt = sync_ + 4096;              // 512
    int*   k3cnt = sync_ + 4608;              // 512

    hipLaunchKernelGGL(pack_kernel, dim3(86), dim3(256), 0, stream,
                       w2, w3, w2t2, (float4*)w3p4f, w3p1, sync_);
    hipLaunchKernelGGL(pack_edgeW_kernel, dim3(2080), dim3(256), 0, stream,
                       w2, w3, W2L, W2R, W3L, W3R);
    hipLaunchKernelGGL(conv1f_kernel, dim3(33, 16), dim3(256), 0, stream,
                       x, w1, b1, g1, be1, m1, v1, a1f);
    hipLaunchKernelGGL(conv2f_kernel, dim3(33, 16), dim3(256), 0, stream,
                       a1f, w2t2, b2, g2, be2, m2, v2, a2f);
    hipLaunchKernelGGL(conv3f_kernel, dim3(17, 16), dim3(256), 0, stream,
                       a2f, (const float4*)w3p4f, w3p1, b3, g3, be3, m3, v3, a3f);
    hipLaunchKernelGGL(fused_kernel, dim3(32 + 32 * 128), dim3(256), 0, stream,
                       x, w1, b1, g1, be1, m1, v1,
                       b2, g2, be2, m2, v2, b3, g3, be3, m3, v3,
                       W2L, W2R, W3L, W3R, a1f, a2f, a3f,
                       a2L, a2R, edgeL, edgeR,
                       wih0, whh0, bih0, bhh0, wih1, whh1, bih1, bhh1,
                       feats, h1o, h2o, cnt0, flag1, k2cnt, k3cnt);
    hipLaunchKernelGGL(fc_kernel, dim3(128), dim3(256), 0, stream,
                       h2o, fc1w, fc1b, fc2w, fc2b, out);
}